// Round 2
// baseline (277.154 us; speedup 1.0000x reference)
//
#include <hip/hip_runtime.h>
#include <hip/hip_bf16.h>
#include <math.h>

#define BB 2
#define SS 2048
#define EE 512
#define HH 8
#define NN (BB*SS)
#define JC1 8   // denoms j-chunks (256 j each)
#define JCP 4   // fused ew+pv j-chunks (512 j each)

typedef __attribute__((ext_vector_type(8))) short short8;
typedef __attribute__((ext_vector_type(4))) float f32x4;

__device__ __forceinline__ float b2f(short v){
    return __uint_as_float(((unsigned)(unsigned short)v) << 16);
}
__device__ __forceinline__ unsigned f2bf(float f){
    unsigned u = __float_as_uint(f);
    u += 0x7fffu + ((u >> 16) & 1u);
    return u >> 16;
}
__device__ __forceinline__ void stage16_f32(const float* __restrict__ src,
                                            __hip_bfloat16* dst){
    const float4 f0 = *reinterpret_cast<const float4*>(src);
    const float4 f1 = *reinterpret_cast<const float4*>(src + 4);
    const float4 f2 = *reinterpret_cast<const float4*>(src + 8);
    const float4 f3 = *reinterpret_cast<const float4*>(src + 12);
    uint4 o0, o1;
    o0.x = f2bf(f0.x) | (f2bf(f0.y) << 16);
    o0.y = f2bf(f0.z) | (f2bf(f0.w) << 16);
    o0.z = f2bf(f1.x) | (f2bf(f1.y) << 16);
    o0.w = f2bf(f1.z) | (f2bf(f1.w) << 16);
    o1.x = f2bf(f2.x) | (f2bf(f2.y) << 16);
    o1.y = f2bf(f2.z) | (f2bf(f2.w) << 16);
    o1.z = f2bf(f3.x) | (f2bf(f3.y) << 16);
    o1.w = f2bf(f3.z) | (f2bf(f3.w) << 16);
    *reinterpret_cast<uint4*>(dst) = o0;
    *reinterpret_cast<uint4*>(dst + 8) = o1;
}
__device__ __forceinline__ void stage16_b16(const __hip_bfloat16* __restrict__ src,
                                            __hip_bfloat16* dst){
    const uint4* s = reinterpret_cast<const uint4*>(src);
    uint4* d = reinterpret_cast<uint4*>(dst);
    d[0] = s[0]; d[1] = s[1];
}

// ---------------- one-time f32 -> bf16 conversion of x + 6 weights ----------------
__global__ void conv_bf16(
    const float* s0, const float* s1, const float* s2, const float* s3,
    const float* s4, const float* s5, const float* s6,
    __hip_bfloat16* d0, __hip_bfloat16* d1, __hip_bfloat16* d2, __hip_bfloat16* d3,
    __hip_bfloat16* d4, __hip_bfloat16* d5, __hip_bfloat16* d6)
{
    const int which = blockIdx.y;
    const float* s; __hip_bfloat16* d; int n;
    switch (which) {
        case 0: s = s0; d = d0; n = 2097152; break;
        case 1: s = s1; d = d1; n = 262144; break;
        case 2: s = s2; d = d2; n = 262144; break;
        case 3: s = s3; d = d3; n = 262144; break;
        case 4: s = s4; d = d4; n = 266240; break;
        case 5: s = s5; d = d5; n = 262144; break;
        default: s = s6; d = d6; n = 262144; break;
    }
    const int base = (blockIdx.x * 256 + threadIdx.x) * 4;
    if (base >= n) return;
    const float4 f = *reinterpret_cast<const float4*>(s + base);
    uint2 o;
    o.x = f2bf(f.x) | (f2bf(f.y) << 16);
    o.y = f2bf(f.z) | (f2bf(f.w) << 16);
    *reinterpret_cast<uint2*>(d + base) = o;
}

// ---------------- fused QKV projection (MFMA) ----------------
template<int B16>
__global__ __launch_bounds__(256) void qkv_gemm(
    const void* __restrict__ x,
    const void* __restrict__ Wq, const float* __restrict__ bq,
    const void* __restrict__ Wk, const float* __restrict__ bk,
    const void* __restrict__ Wv, const float* __restrict__ bv,
    __hip_bfloat16* __restrict__ qb,
    __hip_bfloat16* __restrict__ kb,
    __hip_bfloat16* __restrict__ vT)
{
    __shared__ __hip_bfloat16 As[64][72];
    __shared__ __hip_bfloat16 Bs[64][72];
    const int tid = threadIdx.x;
    const int which = blockIdx.x >> 3;
    const int col0 = (blockIdx.x & 7) * 64;
    const int row0 = blockIdx.y * 64;
    const int wv = tid >> 6, lane = tid & 63, quad = lane >> 4, m16 = lane & 15;
    const int sr = tid >> 2;
    const int sc = (tid & 3) * 16;
    const void* W    = (which == 0) ? Wq : (which == 1) ? Wk : Wv;
    const float* bias = (which == 0) ? bq : (which == 1) ? bk : bv;

    f32x4 acc[4];
    #pragma unroll
    for (int nt = 0; nt < 4; ++nt) acc[nt] = (f32x4){0.f, 0.f, 0.f, 0.f};

    for (int k0 = 0; k0 < 512; k0 += 64) {
        if (B16) {
            stage16_b16((const __hip_bfloat16*)x + (size_t)(row0 + sr) * EE + k0 + sc, &As[sr][sc]);
            stage16_b16((const __hip_bfloat16*)W + (size_t)(col0 + sr) * EE + k0 + sc, &Bs[sr][sc]);
        } else {
            stage16_f32((const float*)x + (size_t)(row0 + sr) * EE + k0 + sc, &As[sr][sc]);
            stage16_f32((const float*)W + (size_t)(col0 + sr) * EE + k0 + sc, &Bs[sr][sc]);
        }
        __syncthreads();
        #pragma unroll
        for (int ks = 0; ks < 2; ++ks) {
            const short8 a = *reinterpret_cast<const short8*>(
                &As[wv * 16 + m16][ks * 32 + quad * 8]);
            #pragma unroll
            for (int nt = 0; nt < 4; ++nt) {
                const short8 b = *reinterpret_cast<const short8*>(
                    &Bs[nt * 16 + m16][ks * 32 + quad * 8]);
                acc[nt] = __builtin_amdgcn_mfma_f32_16x16x32_bf16(a, b, acc[nt], 0, 0, 0);
            }
        }
        __syncthreads();
    }

    if (which == 2) {
        #pragma unroll
        for (int nt = 0; nt < 4; ++nt) {
            const float bb = bias[col0 + nt * 16 + m16];
            #pragma unroll
            for (int r = 0; r < 4; ++r)
                Bs[wv * 16 + quad * 4 + r][nt * 16 + m16] =
                    __float2bfloat16(acc[nt][r] + bb);
        }
        __syncthreads();
        const int bb2 = row0 >> 11;
        const int j0 = row0 & (SS - 1);
        const int er = tid >> 2;
        const int js = (tid & 3) * 16;
        unsigned pk[8];
        #pragma unroll
        for (int p = 0; p < 8; ++p) {
            const unsigned lo = *reinterpret_cast<const unsigned short*>(&Bs[js + 2*p][er]);
            const unsigned hi = *reinterpret_cast<const unsigned short*>(&Bs[js + 2*p + 1][er]);
            pk[p] = lo | (hi << 16);
        }
        uint4 s0; s0.x = pk[0]; s0.y = pk[1]; s0.z = pk[2]; s0.w = pk[3];
        uint4 s1; s1.x = pk[4]; s1.y = pk[5]; s1.z = pk[6]; s1.w = pk[7];
        __hip_bfloat16* dst = vT + ((size_t)(bb2 * EE + col0 + er)) * SS + j0 + js;
        *reinterpret_cast<uint4*>(dst) = s0;
        *reinterpret_cast<uint4*>(dst + 8) = s1;
    } else {
        __hip_bfloat16* C = (which == 0) ? qb : kb;
        #pragma unroll
        for (int nt = 0; nt < 4; ++nt) {
            const int gn = col0 + nt * 16 + m16;
            const float bb = bias[gn];
            #pragma unroll
            for (int r = 0; r < 4; ++r) {
                const int gm = row0 + wv * 16 + quad * 4 + r;
                C[(size_t)gm * EE + gn] = __float2bfloat16(acc[nt][r] + bb);
            }
        }
    }
}

// ---------------- MFMA GEMM (MLP1 / MLP2 / out-proj) ----------------
template<int MODE, int AB16, int WB16, int CF32>
__global__ __launch_bounds__(256) void gemm_bt(
    const void* __restrict__ Av,
    const void* __restrict__ Wv_,
    const float* __restrict__ bias,
    void* __restrict__ Cv,
    int ldb)
{
    __shared__ __hip_bfloat16 As[64][72];
    __shared__ __hip_bfloat16 Bs[64][72];
    const int tid = threadIdx.x;
    const int col0 = blockIdx.x * 64;
    const int row0 = blockIdx.y * 64;
    const int wv = tid >> 6, lane = tid & 63, quad = lane >> 4, m16 = lane & 15;
    const int sr = tid >> 2;
    const int sc = (tid & 3) * 16;

    f32x4 acc[4];
    #pragma unroll
    for (int nt = 0; nt < 4; ++nt) acc[nt] = (f32x4){0.f, 0.f, 0.f, 0.f};

    for (int k0 = 0; k0 < 512; k0 += 64) {
        if (AB16)
            stage16_b16((const __hip_bfloat16*)Av + (size_t)(row0 + sr) * EE + k0 + sc, &As[sr][sc]);
        else
            stage16_f32((const float*)Av + (size_t)(row0 + sr) * EE + k0 + sc, &As[sr][sc]);
        if (WB16)
            stage16_b16((const __hip_bfloat16*)Wv_ + (size_t)(col0 + sr) * ldb + k0 + sc, &Bs[sr][sc]);
        else
            stage16_f32((const float*)Wv_ + (size_t)(col0 + sr) * ldb + k0 + sc, &Bs[sr][sc]);
        __syncthreads();
        #pragma unroll
        for (int ks = 0; ks < 2; ++ks) {
            const short8 a = *reinterpret_cast<const short8*>(
                &As[wv * 16 + m16][ks * 32 + quad * 8]);
            #pragma unroll
            for (int nt = 0; nt < 4; ++nt) {
                const short8 b = *reinterpret_cast<const short8*>(
                    &Bs[nt * 16 + m16][ks * 32 + quad * 8]);
                acc[nt] = __builtin_amdgcn_mfma_f32_16x16x32_bf16(a, b, acc[nt], 0, 0, 0);
            }
        }
        __syncthreads();
    }

    #pragma unroll
    for (int nt = 0; nt < 4; ++nt) {
        const int gn = col0 + nt * 16 + m16;
        float bb = bias[gn];
        if (MODE == 1) {
            float ts = 0.f;
            #pragma unroll
            for (int h = 0; h < 8; ++h) {
                const size_t wi = (size_t)gn * ldb + 512 + h;
                ts += WB16 ? (float)((const __hip_bfloat16*)Wv_)[wi]
                           : ((const float*)Wv_)[wi];
            }
            bb += ts * (1.0f / (float)SS);
        }
        #pragma unroll
        for (int r = 0; r < 4; ++r) {
            const int gm = row0 + wv * 16 + quad * 4 + r;
            const size_t ci = (size_t)gm * EE + gn;
            float c = acc[nt][r] + bb;
            if (MODE == 1) c = 0.5f * c * (1.0f + erff(c * 0.70710678118654752f));
            if (MODE == 2) c += (float)((const __hip_bfloat16*)Cv)[ci];
            if (CF32) ((float*)Cv)[ci] = c;
            else      ((__hip_bfloat16*)Cv)[ci] = __float2bfloat16(c);
        }
    }
}

// ---------------- K1: partial softmax denominators ----------------
// Double-buffered K tile, 1 barrier per 16-j tile, issue-early/write-late (T14):
// global loads for tile jt+1 issue before the MFMA+exp work on tile jt,
// LDS writes land after it. No vmcnt stall on the critical path.
__global__ __launch_bounds__(256) void attn_denoms(
    const __hip_bfloat16* __restrict__ qws,
    const __hip_bfloat16* __restrict__ kws,
    float* __restrict__ dnP,
    int* __restrict__ cntI)
{
    __shared__ __hip_bfloat16 KL[2][16][520];   // 33.3 KB
    const int tid = threadIdx.x;
    const int wv = tid >> 6, lane = tid & 63, quad = lane >> 4, m16 = lane & 15;
    const int jc = blockIdx.x;              // 8 chunks x 256 j
    const int it = blockIdx.y;              // 32 tiles x 64 i
    const int b  = blockIdx.z;
    const size_t g0 = (size_t)b * SS + it * 64;
    const size_t gb = (size_t)b * SS;

    if (jc == 0 && tid < 64) cntI[g0 + tid] = 0;

    short8 aq[HH][2];
    #pragma unroll
    for (int h = 0; h < HH; ++h)
        #pragma unroll
        for (int ks = 0; ks < 2; ++ks)
            aq[h][ks] = *reinterpret_cast<const short8*>(
                qws + (g0 + wv * 16 + m16) * EE + h * 64 + ks * 32 + quad * 8);

    float dph[HH][4];
    #pragma unroll
    for (int h = 0; h < HH; ++h)
        #pragma unroll
        for (int r = 0; r < 4; ++r) dph[h][r] = 0.f;

    const int srow = tid >> 4, scol = (tid & 15) * 32;
    {   // initial stage: tile 0 -> KL[0]
        const uint4* src = reinterpret_cast<const uint4*>(
            kws + (gb + jc * 256 + srow) * EE + scol);
        uint4* dst = reinterpret_cast<uint4*>(&KL[0][srow][scol]);
        dst[0] = src[0]; dst[1] = src[1]; dst[2] = src[2]; dst[3] = src[3];
    }

    for (int jt = 0; jt < 16; ++jt) {
        __syncthreads();                       // KL[jt&1] ready
        uint4 kr[4];
        if (jt + 1 < 16) {                     // issue-early: next tile -> regs
            const uint4* src = reinterpret_cast<const uint4*>(
                kws + (gb + jc * 256 + (jt + 1) * 16 + srow) * EE + scol);
            kr[0] = src[0]; kr[1] = src[1]; kr[2] = src[2]; kr[3] = src[3];
        }
        #pragma unroll
        for (int h = 0; h < HH; ++h) {
            const short8 b0 = *reinterpret_cast<const short8*>(&KL[jt & 1][m16][h * 64 + quad * 8]);
            const short8 b1 = *reinterpret_cast<const short8*>(&KL[jt & 1][m16][h * 64 + 32 + quad * 8]);
            f32x4 c = {0.f, 0.f, 0.f, 0.f};
            c = __builtin_amdgcn_mfma_f32_16x16x32_bf16(aq[h][0], b0, c, 0, 0, 0);
            c = __builtin_amdgcn_mfma_f32_16x16x32_bf16(aq[h][1], b1, c, 0, 0, 0);
            #pragma unroll
            for (int r = 0; r < 4; ++r) dph[h][r] += __expf(c[r] * 0.125f);
        }
        if (jt + 1 < 16) {                     // write-late into the spare buffer
            uint4* dst = reinterpret_cast<uint4*>(&KL[(jt + 1) & 1][srow][scol]);
            dst[0] = kr[0]; dst[1] = kr[1]; dst[2] = kr[2]; dst[3] = kr[3];
        }
    }

    #pragma unroll
    for (int h = 0; h < HH; ++h)
        #pragma unroll
        for (int off = 1; off <= 8; off <<= 1)
            #pragma unroll
            for (int r = 0; r < 4; ++r) dph[h][r] += __shfl_xor(dph[h][r], off, 64);
    if (m16 == 0) {
        const size_t i = (size_t)it * 64 + wv * 16 + quad * 4;
        #pragma unroll
        for (int h = 0; h < HH; ++h)
            #pragma unroll
            for (int r = 0; r < 4; ++r)
                dnP[((size_t)(jc * BB + b) * SS + i + r) * HH + h] = dph[h][r];
    }
}

// ---------------- K2: fused ew + PV (pipelined, V direct from global) ----------------
// Block = 32 i x 512 j. LDS: 2x-buffered K (66.6 KB) + ewT + invd = 70.1 KB -> 2 blocks/CU.
// Per step: sync; issue V frags (this step) + K tile (next step) to regs; scores+ewT;
// sync; ds_write K regs; PV from registers. V is never LDS-staged (no intra-block reuse).
__global__ __launch_bounds__(256, 2) void attn_ewpv(
    const __hip_bfloat16* __restrict__ qws,
    const __hip_bfloat16* __restrict__ kws,
    const __hip_bfloat16* __restrict__ vTg,
    const float* __restrict__ dnP,
    int* __restrict__ cntI,
    int* __restrict__ slotJ,
    float* __restrict__ slotW,
    __hip_bfloat16* __restrict__ pvP)
{
    __shared__ __hip_bfloat16 KL[2][32][520];  // 66.6 KB (KL[0] reused as epilogue bounce)
    __shared__ __hip_bfloat16 ewT[32][40];     // 2.6 KB
    __shared__ float invd[HH][32];             // 1 KB
    const int tid = threadIdx.x;
    const int wv = tid >> 6, lane = tid & 63, quad = lane >> 4, m16 = lane & 15;
    const int jc = blockIdx.x;               // 4 chunks x 512 j
    const int it = blockIdx.y;               // 64 tiles x 32 i
    const int b  = blockIdx.z;
    const size_t gb = (size_t)b * SS;
    const size_t g0 = gb + it * 32;
    const int ih = wv & 1;                   // i-half for score phase
    const int jh = wv >> 1;                  // j-half for score phase

    {   // denominators -> 0.125/D (head-mean folded in); 256 thr = HH*32 exactly
        const int h = tid >> 5, i = tid & 31;
        float s = 0.f;
        #pragma unroll
        for (int c = 0; c < JC1; ++c)
            s += dnP[((size_t)(c * BB + b) * SS + it * 32 + i) * HH + h];
        invd[h][i] = 0.125f / s;
    }

    short8 aq[HH][2];
    #pragma unroll
    for (int h = 0; h < HH; ++h)
        #pragma unroll
        for (int ks = 0; ks < 2; ++ks)
            aq[h][ks] = *reinterpret_cast<const short8*>(
                qws + (g0 + ih * 16 + m16) * EE + h * 64 + ks * 32 + quad * 8);

    f32x4 acc[2][8];
    #pragma unroll
    for (int mf = 0; mf < 2; ++mf)
        #pragma unroll
        for (int nf = 0; nf < 8; ++nf) acc[mf][nf] = (f32x4){0.f, 0.f, 0.f, 0.f};

    const int krow = tid >> 4, kcol = (tid & 15) * 32;
    {   // initial stage: K subtile 0 -> KL[0]
        #pragma unroll
        for (int rr = 0; rr < 2; ++rr) {
            const uint4* src = reinterpret_cast<const uint4*>(
                kws + (gb + jc * 512 + rr * 16 + krow) * EE + kcol);
            uint4* dst = reinterpret_cast<uint4*>(&KL[0][rr * 16 + krow][kcol]);
            dst[0] = src[0]; dst[1] = src[1]; dst[2] = src[2]; dst[3] = src[3];
        }
    }
    // per-lane V row base: e = wv*128 + nf*16 + m16, k-offset = quad*8
    const __hip_bfloat16* vrow0 = vTg + ((size_t)b * EE + wv * 128 + m16) * SS + quad * 8;

    for (int st = 0; st < 16; ++st) {
        const int j0 = jc * 512 + st * 32;
        __syncthreads();                       // KL[st&1] staged; ewT free

        // issue-early: V B-frags for THIS step (consumed in PV after sync2)
        short8 vb[8];
        #pragma unroll
        for (int nf = 0; nf < 8; ++nf)
            vb[nf] = *reinterpret_cast<const short8*>(vrow0 + (size_t)(nf * 16) * SS + j0);
        // issue-early: K subtile for NEXT step -> regs
        uint4 kr[8];
        if (st + 1 < 16) {
            #pragma unroll
            for (int rr = 0; rr < 2; ++rr) {
                const uint4* src = reinterpret_cast<const uint4*>(
                    kws + (gb + j0 + 32 + rr * 16 + krow) * EE + kcol);
                kr[rr * 4 + 0] = src[0]; kr[rr * 4 + 1] = src[1];
                kr[rr * 4 + 2] = src[2]; kr[rr * 4 + 3] = src[3];
            }
        }

        // scores: wave's (ih, jh) quadrant of the 32x32 tile, all heads
        float wsum[4] = {0.f, 0.f, 0.f, 0.f};
        #pragma unroll
        for (int h = 0; h < HH; ++h) {
            const short8 b0 = *reinterpret_cast<const short8*>(
                &KL[st & 1][jh * 16 + m16][h * 64 + quad * 8]);
            const short8 b1 = *reinterpret_cast<const short8*>(
                &KL[st & 1][jh * 16 + m16][h * 64 + 32 + quad * 8]);
            f32x4 c = {0.f, 0.f, 0.f, 0.f};
            c = __builtin_amdgcn_mfma_f32_16x16x32_bf16(aq[h][0], b0, c, 0, 0, 0);
            c = __builtin_amdgcn_mfma_f32_16x16x32_bf16(aq[h][1], b1, c, 0, 0, 0);
            #pragma unroll
            for (int r = 0; r < 4; ++r)
                wsum[r] += __expf(c[r] * 0.125f) * invd[h][ih * 16 + quad * 4 + r];
        }
        #pragma unroll
        for (int r = 0; r < 4; ++r) {
            const __hip_bfloat16 wb = __float2bfloat16(wsum[r]);
            ewT[ih * 16 + quad * 4 + r][jh * 16 + m16] = wb;
            if ((float)wb > 0.1f) {            // rare: adjacency crossing
                const int li = ih * 16 + quad * 4 + r;
                const int idx = atomicAdd(&cntI[g0 + li], 1);
                if (idx < 16) {
                    slotJ[((size_t)g0 + li) * 16 + idx] = j0 + jh * 16 + m16;
                    slotW[((size_t)g0 + li) * 16 + idx] = (float)wb;
                }
            }
        }
        __syncthreads();                       // ewT ready

        // write-late: K(st+1) regs -> spare LDS buffer (vmcnt wait lands here)
        if (st + 1 < 16) {
            #pragma unroll
            for (int rr = 0; rr < 2; ++rr) {
                uint4* dst = reinterpret_cast<uint4*>(&KL[(st + 1) & 1][rr * 16 + krow][kcol]);
                dst[0] = kr[rr * 4 + 0]; dst[1] = kr[rr * 4 + 1];
                dst[2] = kr[rr * 4 + 2]; dst[3] = kr[rr * 4 + 3];
            }
        }

        // PV: each wave owns 128 e-cols; A = ew tile (all 32 i), B = V regs
        {
            const short8 a0 = *reinterpret_cast<const short8*>(&ewT[m16][quad * 8]);
            const short8 a1 = *reinterpret_cast<const short8*>(&ewT[16 + m16][quad * 8]);
            #pragma unroll
            for (int nf = 0; nf < 8; ++nf) {
                acc[0][nf] = __builtin_amdgcn_mfma_f32_16x16x32_bf16(a0, vb[nf], acc[0][nf], 0, 0, 0);
                acc[1][nf] = __builtin_amdgcn_mfma_f32_16x16x32_bf16(a1, vb[nf], acc[1][nf], 0, 0, 0);
            }
        }
    }

    // epilogue: bounce acc through KL[0] for coalesced bf16 writes
    #pragma unroll
    for (int mf = 0; mf < 2; ++mf)
        #pragma unroll
        for (int nf = 0; nf < 8; ++nf)
            #pragma unroll
            for (int r = 0; r < 4; ++r)
                KL[0][mf * 16 + quad * 4 + r][wv * 128 + nf * 16 + m16] =
                    __float2bfloat16(acc[mf][nf][r]);
    __syncthreads();
    const int orow = tid >> 3;
    const int oc = (tid & 7) * 64;
    const uint4* s = reinterpret_cast<const uint4*>(&KL[0][orow][oc]);
    uint4* d = reinterpret_cast<uint4*>(
        pvP + ((size_t)jc * NN + g0 + orow) * EE + oc);
    #pragma unroll
    for (int q = 0; q < 8; ++q) d[q] = s[q];
}

// ---------------- K3: combine PV partials + rare messages path ----------------
__global__ __launch_bounds__(256) void pv_combine(
    const __hip_bfloat16* __restrict__ pvP,
    const int* __restrict__ cntI,
    const int* __restrict__ slotJ,
    const float* __restrict__ slotW,
    const float* __restrict__ x,
    __hip_bfloat16* __restrict__ u1out)
{
    const int tid = threadIdx.x;
    const int row = blockIdx.x * 4 + (tid >> 6);   // [0, NN)
    const int e0 = (tid & 63) * 8;
    float s[8] = {0.f, 0.f, 0.f, 0.f, 0.f, 0.f, 0.f, 0.f};
    #pragma unroll
    for (int c = 0; c < JCP; ++c) {
        const short8 v = *reinterpret_cast<const short8*>(
            pvP + ((size_t)c * NN + row) * EE + e0);
        #pragma unroll
        for (int k = 0; k < 8; ++k) s[k] += b2f(v[k]);
    }
    const int cn = cntI[row];
    if (cn > 0) {                                  // exact rare path: masked mean
        const float inv = 1.f / (float)cn;
        const int ns = cn < 16 ? cn : 16;
        const int b = row >> 11;
        for (int t = 0; t < ns; ++t) {
            const int j = slotJ[(size_t)row * 16 + t];
            const float w = slotW[(size_t)row * 16 + t] * inv;
            const float* xr = x + ((size_t)b * SS + j) * EE + e0;
            #pragma unroll
            for (int k = 0; k < 8; ++k) s[k] += w * xr[k];
        }
    }
    short8 o;
    #pragma unroll
    for (int k = 0; k < 8; ++k) o[k] = (short)f2bf(s[k]);
    *reinterpret_cast<short8*>(u1out + (size_t)row * EE + e0) = o;
}

extern "C" void kernel_launch(void* const* d_in, const int* in_sizes, int n_in,
                              void* d_out, int out_size, void* d_ws, size_t ws_size,
                              hipStream_t stream)
{
    const float* x   = (const float*)d_in[0];
    const float* Wq  = (const float*)d_in[1];
    const float* bq  = (const float*)d_in[2];
    const float* Wk  = (const float*)d_in[3];
    const float* bk  = (const float*)d_in[4];
    const float* Wv  = (const float*)d_in[5];
    const float* bv  = (const float*)d_in[6];
    const float* Wm1 = (const float*)d_in[7];
    const float* bm1 = (const float*)d_in[8];
    const float* Wm2 = (const float*)d_in[9];
    const float* bm2 = (const float*)d_in[10];
    const float* Wo  = (const float*)d_in[11];
    const float* bo  = (const float*)d_in[12];

    char* ws = (char*)d_ws;
    const size_t MB = 1024 * 1024;
    __hip_bfloat16* qb = (__hip_bfloat16*)(ws + 0);        // q -> u1 -> t   4MB
    __hip_bfloat16* kb = (__hip_bfloat16*)(ws + 4*MB);     // k -> hm        4MB
    __hip_bfloat16* vT = (__hip_bfloat16*)(ws + 8*MB);     // V^T [b][e][j]  4MB
    __hip_bfloat16* pvP = (__hip_bfloat16*)(ws + 12*MB);   // PV partials [4][NN][EE] 16MB
    float* dnP = (float*)(ws + 28*MB);                     // denom partials 1MB
    int*   cntI = (int*)(ws + 29*MB);                      // neighbor cnt  16KB
    int*   slotJ = (int*)(ws + 29*MB + 64*1024);           // crossing j    256KB
    float* slotW = (float*)(ws + 29*MB + 384*1024);        // crossing w    256KB
    const bool EXT = (ws_size >= 38 * MB);
    __hip_bfloat16* xb   = (__hip_bfloat16*)(ws + 30*MB);          // 4MB
    __hip_bfloat16* wqb  = (__hip_bfloat16*)(ws + 34*MB);
    __hip_bfloat16* wkb  = (__hip_bfloat16*)(ws + 34*MB + 512*1024);
    __hip_bfloat16* wvb  = (__hip_bfloat16*)(ws + 35*MB);
    __hip_bfloat16* wm1b = (__hip_bfloat16*)(ws + 35*MB + 512*1024);
    __hip_bfloat16* wm2b = (__hip_bfloat16*)(ws + 36*MB + 256*1024);
    __hip_bfloat16* wob  = (__hip_bfloat16*)(ws + 36*MB + 768*1024);

    dim3 blk(256, 1, 1);
    dim3 gg(EE / 64, NN / 64, 1);

    if (EXT) {
        conv_bf16<<<dim3(2048, 7, 1), blk, 0, stream>>>(
            x, Wq, Wk, Wv, Wm1, Wm2, Wo, xb, wqb, wkb, wvb, wm1b, wm2b, wob);
        qkv_gemm<1><<<dim3(24, NN / 64, 1), blk, 0, stream>>>(
            xb, wqb, bq, wkb, bk, wvb, bv, qb, kb, vT);
    } else {
        qkv_gemm<0><<<dim3(24, NN / 64, 1), blk, 0, stream>>>(
            x, Wq, bq, Wk, bk, Wv, bv, qb, kb, vT);
    }
    attn_denoms<<<dim3(JC1, SS / 64, BB), blk, 0, stream>>>(qb, kb, dnP, cntI);
    attn_ewpv<<<dim3(JCP, SS / 32, BB), blk, 0, stream>>>(
        qb, kb, vT, dnP, cntI, slotJ, slotW, pvP);
    pv_combine<<<dim3(NN / 4, 1, 1), blk, 0, stream>>>(
        pvP, cntI, slotJ, slotW, x, qb);                            // u1 -> qb
    if (EXT) {
        gemm_bt<1,1,1,0><<<gg, blk, 0, stream>>>(xb, wm1b, bm1, kb, EE + HH);
        gemm_bt<2,1,1,0><<<gg, blk, 0, stream>>>(kb, wm2b, bm2, qb, EE);
        gemm_bt<0,1,1,1><<<gg, blk, 0, stream>>>(qb, wob, bo, d_out, EE);
    } else {
        gemm_bt<1,0,0,0><<<gg, blk, 0, stream>>>(x, Wm1, bm1, kb, EE + HH);
        gemm_bt<2,1,0,0><<<gg, blk, 0, stream>>>(kb, Wm2, bm2, qb, EE);
        gemm_bt<0,1,0,1><<<gg, blk, 0, stream>>>(qb, Wo, bo, d_out, EE);
    }
}

// Round 4
// 231.744 us; speedup vs baseline: 1.1959x; 1.1959x over previous
//
#include <hip/hip_runtime.h>
#include <hip/hip_bf16.h>
#include <math.h>

#define BB 2
#define SS 2048
#define EE 512
#define HH 8
#define NN (BB*SS)
#define JC1 8   // denoms j-chunks (256 j each)
#define JCP 4   // fused ew+pv j-chunks (512 j each)

typedef __attribute__((ext_vector_type(8))) short short8;
typedef __attribute__((ext_vector_type(4))) float f32x4;

__device__ __forceinline__ float b2f(short v){
    return __uint_as_float(((unsigned)(unsigned short)v) << 16);
}
__device__ __forceinline__ unsigned f2bf(float f){
    unsigned u = __float_as_uint(f);
    u += 0x7fffu + ((u >> 16) & 1u);
    return u >> 16;
}
__device__ __forceinline__ void stage16_f32(const float* __restrict__ src,
                                            __hip_bfloat16* dst){
    const float4 f0 = *reinterpret_cast<const float4*>(src);
    const float4 f1 = *reinterpret_cast<const float4*>(src + 4);
    const float4 f2 = *reinterpret_cast<const float4*>(src + 8);
    const float4 f3 = *reinterpret_cast<const float4*>(src + 12);
    uint4 o0, o1;
    o0.x = f2bf(f0.x) | (f2bf(f0.y) << 16);
    o0.y = f2bf(f0.z) | (f2bf(f0.w) << 16);
    o0.z = f2bf(f1.x) | (f2bf(f1.y) << 16);
    o0.w = f2bf(f1.z) | (f2bf(f1.w) << 16);
    o1.x = f2bf(f2.x) | (f2bf(f2.y) << 16);
    o1.y = f2bf(f2.z) | (f2bf(f2.w) << 16);
    o1.z = f2bf(f3.x) | (f2bf(f3.y) << 16);
    o1.w = f2bf(f3.z) | (f2bf(f3.w) << 16);
    *reinterpret_cast<uint4*>(dst) = o0;
    *reinterpret_cast<uint4*>(dst + 8) = o1;
}
__device__ __forceinline__ void stage16_b16(const __hip_bfloat16* __restrict__ src,
                                            __hip_bfloat16* dst){
    const uint4* s = reinterpret_cast<const uint4*>(src);
    uint4* d = reinterpret_cast<uint4*>(dst);
    d[0] = s[0]; d[1] = s[1];
}

// ---------------- one-time f32 -> bf16 conversion of x + 6 weights ----------------
__global__ void conv_bf16(
    const float* s0, const float* s1, const float* s2, const float* s3,
    const float* s4, const float* s5, const float* s6,
    __hip_bfloat16* d0, __hip_bfloat16* d1, __hip_bfloat16* d2, __hip_bfloat16* d3,
    __hip_bfloat16* d4, __hip_bfloat16* d5, __hip_bfloat16* d6)
{
    const int which = blockIdx.y;
    const float* s; __hip_bfloat16* d; int n;
    switch (which) {
        case 0: s = s0; d = d0; n = 2097152; break;
        case 1: s = s1; d = d1; n = 262144; break;
        case 2: s = s2; d = d2; n = 262144; break;
        case 3: s = s3; d = d3; n = 262144; break;
        case 4: s = s4; d = d4; n = 266240; break;
        case 5: s = s5; d = d5; n = 262144; break;
        default: s = s6; d = d6; n = 262144; break;
    }
    const int base = (blockIdx.x * 256 + threadIdx.x) * 4;
    if (base >= n) return;
    const float4 f = *reinterpret_cast<const float4*>(s + base);
    uint2 o;
    o.x = f2bf(f.x) | (f2bf(f.y) << 16);
    o.y = f2bf(f.z) | (f2bf(f.w) << 16);
    *reinterpret_cast<uint2*>(d + base) = o;
}

// ---------------- fused QKV projection (MFMA) ----------------
template<int B16>
__global__ __launch_bounds__(256) void qkv_gemm(
    const void* __restrict__ x,
    const void* __restrict__ Wq, const float* __restrict__ bq,
    const void* __restrict__ Wk, const float* __restrict__ bk,
    const void* __restrict__ Wv, const float* __restrict__ bv,
    __hip_bfloat16* __restrict__ qb,
    __hip_bfloat16* __restrict__ kb,
    __hip_bfloat16* __restrict__ vT)
{
    __shared__ __hip_bfloat16 As[64][72];
    __shared__ __hip_bfloat16 Bs[64][72];
    const int tid = threadIdx.x;
    const int which = blockIdx.x >> 3;
    const int col0 = (blockIdx.x & 7) * 64;
    const int row0 = blockIdx.y * 64;
    const int wv = tid >> 6, lane = tid & 63, quad = lane >> 4, m16 = lane & 15;
    const int sr = tid >> 2;
    const int sc = (tid & 3) * 16;
    const void* W    = (which == 0) ? Wq : (which == 1) ? Wk : Wv;
    const float* bias = (which == 0) ? bq : (which == 1) ? bk : bv;

    f32x4 acc[4];
    #pragma unroll
    for (int nt = 0; nt < 4; ++nt) acc[nt] = (f32x4){0.f, 0.f, 0.f, 0.f};

    for (int k0 = 0; k0 < 512; k0 += 64) {
        if (B16) {
            stage16_b16((const __hip_bfloat16*)x + (size_t)(row0 + sr) * EE + k0 + sc, &As[sr][sc]);
            stage16_b16((const __hip_bfloat16*)W + (size_t)(col0 + sr) * EE + k0 + sc, &Bs[sr][sc]);
        } else {
            stage16_f32((const float*)x + (size_t)(row0 + sr) * EE + k0 + sc, &As[sr][sc]);
            stage16_f32((const float*)W + (size_t)(col0 + sr) * EE + k0 + sc, &Bs[sr][sc]);
        }
        __syncthreads();
        #pragma unroll
        for (int ks = 0; ks < 2; ++ks) {
            const short8 a = *reinterpret_cast<const short8*>(
                &As[wv * 16 + m16][ks * 32 + quad * 8]);
            #pragma unroll
            for (int nt = 0; nt < 4; ++nt) {
                const short8 b = *reinterpret_cast<const short8*>(
                    &Bs[nt * 16 + m16][ks * 32 + quad * 8]);
                acc[nt] = __builtin_amdgcn_mfma_f32_16x16x32_bf16(a, b, acc[nt], 0, 0, 0);
            }
        }
        __syncthreads();
    }

    if (which == 2) {
        #pragma unroll
        for (int nt = 0; nt < 4; ++nt) {
            const float bb = bias[col0 + nt * 16 + m16];
            #pragma unroll
            for (int r = 0; r < 4; ++r)
                Bs[wv * 16 + quad * 4 + r][nt * 16 + m16] =
                    __float2bfloat16(acc[nt][r] + bb);
        }
        __syncthreads();
        const int bb2 = row0 >> 11;
        const int j0 = row0 & (SS - 1);
        const int er = tid >> 2;
        const int js = (tid & 3) * 16;
        unsigned pk[8];
        #pragma unroll
        for (int p = 0; p < 8; ++p) {
            const unsigned lo = *reinterpret_cast<const unsigned short*>(&Bs[js + 2*p][er]);
            const unsigned hi = *reinterpret_cast<const unsigned short*>(&Bs[js + 2*p + 1][er]);
            pk[p] = lo | (hi << 16);
        }
        uint4 s0; s0.x = pk[0]; s0.y = pk[1]; s0.z = pk[2]; s0.w = pk[3];
        uint4 s1; s1.x = pk[4]; s1.y = pk[5]; s1.z = pk[6]; s1.w = pk[7];
        __hip_bfloat16* dst = vT + ((size_t)(bb2 * EE + col0 + er)) * SS + j0 + js;
        *reinterpret_cast<uint4*>(dst) = s0;
        *reinterpret_cast<uint4*>(dst + 8) = s1;
    } else {
        __hip_bfloat16* C = (which == 0) ? qb : kb;
        #pragma unroll
        for (int nt = 0; nt < 4; ++nt) {
            const int gn = col0 + nt * 16 + m16;
            const float bb = bias[gn];
            #pragma unroll
            for (int r = 0; r < 4; ++r) {
                const int gm = row0 + wv * 16 + quad * 4 + r;
                C[(size_t)gm * EE + gn] = __float2bfloat16(acc[nt][r] + bb);
            }
        }
    }
}

// ---------------- MFMA GEMM (MLP1 / MLP2 / out-proj) ----------------
template<int MODE, int AB16, int WB16, int CF32>
__global__ __launch_bounds__(256) void gemm_bt(
    const void* __restrict__ Av,
    const void* __restrict__ Wv_,
    const float* __restrict__ bias,
    void* __restrict__ Cv,
    int ldb)
{
    __shared__ __hip_bfloat16 As[64][72];
    __shared__ __hip_bfloat16 Bs[64][72];
    const int tid = threadIdx.x;
    const int col0 = blockIdx.x * 64;
    const int row0 = blockIdx.y * 64;
    const int wv = tid >> 6, lane = tid & 63, quad = lane >> 4, m16 = lane & 15;
    const int sr = tid >> 2;
    const int sc = (tid & 3) * 16;

    f32x4 acc[4];
    #pragma unroll
    for (int nt = 0; nt < 4; ++nt) acc[nt] = (f32x4){0.f, 0.f, 0.f, 0.f};

    for (int k0 = 0; k0 < 512; k0 += 64) {
        if (AB16)
            stage16_b16((const __hip_bfloat16*)Av + (size_t)(row0 + sr) * EE + k0 + sc, &As[sr][sc]);
        else
            stage16_f32((const float*)Av + (size_t)(row0 + sr) * EE + k0 + sc, &As[sr][sc]);
        if (WB16)
            stage16_b16((const __hip_bfloat16*)Wv_ + (size_t)(col0 + sr) * ldb + k0 + sc, &Bs[sr][sc]);
        else
            stage16_f32((const float*)Wv_ + (size_t)(col0 + sr) * ldb + k0 + sc, &Bs[sr][sc]);
        __syncthreads();
        #pragma unroll
        for (int ks = 0; ks < 2; ++ks) {
            const short8 a = *reinterpret_cast<const short8*>(
                &As[wv * 16 + m16][ks * 32 + quad * 8]);
            #pragma unroll
            for (int nt = 0; nt < 4; ++nt) {
                const short8 b = *reinterpret_cast<const short8*>(
                    &Bs[nt * 16 + m16][ks * 32 + quad * 8]);
                acc[nt] = __builtin_amdgcn_mfma_f32_16x16x32_bf16(a, b, acc[nt], 0, 0, 0);
            }
        }
        __syncthreads();
    }

    #pragma unroll
    for (int nt = 0; nt < 4; ++nt) {
        const int gn = col0 + nt * 16 + m16;
        float bb = bias[gn];
        if (MODE == 1) {
            float ts = 0.f;
            #pragma unroll
            for (int h = 0; h < 8; ++h) {
                const size_t wi = (size_t)gn * ldb + 512 + h;
                ts += WB16 ? (float)((const __hip_bfloat16*)Wv_)[wi]
                           : ((const float*)Wv_)[wi];
            }
            bb += ts * (1.0f / (float)SS);
        }
        #pragma unroll
        for (int r = 0; r < 4; ++r) {
            const int gm = row0 + wv * 16 + quad * 4 + r;
            const size_t ci = (size_t)gm * EE + gn;
            float c = acc[nt][r] + bb;
            if (MODE == 1) c = 0.5f * c * (1.0f + erff(c * 0.70710678118654752f));
            if (MODE == 2) c += (float)((const __hip_bfloat16*)Cv)[ci];
            if (CF32) ((float*)Cv)[ci] = c;
            else      ((__hip_bfloat16*)Cv)[ci] = __float2bfloat16(c);
        }
    }
}

// ---------------- K1: partial softmax denominators ----------------
// Double-buffered K tile, 1 barrier per 16-j tile, issue-early/write-late:
// proven ~neutral-positive in R2, register demand fits (no spill observed).
__global__ __launch_bounds__(256) void attn_denoms(
    const __hip_bfloat16* __restrict__ qws,
    const __hip_bfloat16* __restrict__ kws,
    float* __restrict__ dnP,
    int* __restrict__ cntI)
{
    __shared__ __hip_bfloat16 KL[2][16][520];   // 33.3 KB
    const int tid = threadIdx.x;
    const int wv = tid >> 6, lane = tid & 63, quad = lane >> 4, m16 = lane & 15;
    const int jc = blockIdx.x;              // 8 chunks x 256 j
    const int it = blockIdx.y;              // 32 tiles x 64 i
    const int b  = blockIdx.z;
    const size_t g0 = (size_t)b * SS + it * 64;
    const size_t gb = (size_t)b * SS;

    if (jc == 0 && tid < 64) cntI[g0 + tid] = 0;

    short8 aq[HH][2];
    #pragma unroll
    for (int h = 0; h < HH; ++h)
        #pragma unroll
        for (int ks = 0; ks < 2; ++ks)
            aq[h][ks] = *reinterpret_cast<const short8*>(
                qws + (g0 + wv * 16 + m16) * EE + h * 64 + ks * 32 + quad * 8);

    float dph[HH][4];
    #pragma unroll
    for (int h = 0; h < HH; ++h)
        #pragma unroll
        for (int r = 0; r < 4; ++r) dph[h][r] = 0.f;

    const int srow = tid >> 4, scol = (tid & 15) * 32;
    {   // initial stage: tile 0 -> KL[0]
        const uint4* src = reinterpret_cast<const uint4*>(
            kws + (gb + jc * 256 + srow) * EE + scol);
        uint4* dst = reinterpret_cast<uint4*>(&KL[0][srow][scol]);
        dst[0] = src[0]; dst[1] = src[1]; dst[2] = src[2]; dst[3] = src[3];
    }

    for (int jt = 0; jt < 16; ++jt) {
        __syncthreads();                       // KL[jt&1] ready
        uint4 kr[4];
        if (jt + 1 < 16) {                     // issue-early: next tile -> regs
            const uint4* src = reinterpret_cast<const uint4*>(
                kws + (gb + jc * 256 + (jt + 1) * 16 + srow) * EE + scol);
            kr[0] = src[0]; kr[1] = src[1]; kr[2] = src[2]; kr[3] = src[3];
        }
        #pragma unroll
        for (int h = 0; h < HH; ++h) {
            const short8 b0 = *reinterpret_cast<const short8*>(&KL[jt & 1][m16][h * 64 + quad * 8]);
            const short8 b1 = *reinterpret_cast<const short8*>(&KL[jt & 1][m16][h * 64 + 32 + quad * 8]);
            f32x4 c = {0.f, 0.f, 0.f, 0.f};
            c = __builtin_amdgcn_mfma_f32_16x16x32_bf16(aq[h][0], b0, c, 0, 0, 0);
            c = __builtin_amdgcn_mfma_f32_16x16x32_bf16(aq[h][1], b1, c, 0, 0, 0);
            #pragma unroll
            for (int r = 0; r < 4; ++r) dph[h][r] += __expf(c[r] * 0.125f);
        }
        if (jt + 1 < 16) {                     // write-late into the spare buffer
            uint4* dst = reinterpret_cast<uint4*>(&KL[(jt + 1) & 1][srow][scol]);
            dst[0] = kr[0]; dst[1] = kr[1]; dst[2] = kr[2]; dst[3] = kr[3];
        }
    }

    #pragma unroll
    for (int h = 0; h < HH; ++h)
        #pragma unroll
        for (int off = 1; off <= 8; off <<= 1)
            #pragma unroll
            for (int r = 0; r < 4; ++r) dph[h][r] += __shfl_xor(dph[h][r], off, 64);
    if (m16 == 0) {
        const size_t i = (size_t)it * 64 + wv * 16 + quad * 4;
        #pragma unroll
        for (int h = 0; h < HH; ++h)
            #pragma unroll
            for (int r = 0; r < 4; ++r)
                dnP[((size_t)(jc * BB + b) * SS + i + r) * HH + h] = dph[h][r];
    }
}

// ---------------- K2: fused ew + PV (single-buffer K, V direct, low pressure) ----------------
// Block = 32 i x 512 j. LDS: KL 33.3 + ewT 2.6 + invd 1 = 36.9 KB -> 4 blocks/CU.
// Per step: stage K -> LDS; sync; scores -> ewT; sync; V frags global -> regs (late,
// minimal live range) -> PV MFMA. No VL staging (V has zero intra-block reuse);
// no K prefetch regs (R2's spill source). 2 barriers/step.
__global__ __launch_bounds__(256, 2) void attn_ewpv(
    const __hip_bfloat16* __restrict__ qws,
    const __hip_bfloat16* __restrict__ kws,
    const __hip_bfloat16* __restrict__ vTg,
    const float* __restrict__ dnP,
    int* __restrict__ cntI,
    int* __restrict__ slotJ,
    float* __restrict__ slotW,
    __hip_bfloat16* __restrict__ pvP)
{
    __shared__ __hip_bfloat16 KL[32][520];     // 33.3 KB (reused as epilogue bounce)
    __shared__ __hip_bfloat16 ewT[32][40];     // 2.6 KB
    __shared__ float invd[HH][32];             // 1 KB
    const int tid = threadIdx.x;
    const int wv = tid >> 6, lane = tid & 63, quad = lane >> 4, m16 = lane & 15;
    const int jc = blockIdx.x;               // 4 chunks x 512 j
    const int it = blockIdx.y;               // 64 tiles x 32 i
    const int b  = blockIdx.z;
    const size_t gb = (size_t)b * SS;
    const size_t g0 = gb + it * 32;
    const int ih = wv & 1;                   // i-half for score phase
    const int jh = wv >> 1;                  // j-half for score phase

    {   // denominators -> 0.125/D (head-mean folded in); 256 thr = HH*32 exactly
        const int h = tid >> 5, i = tid & 31;
        float s = 0.f;
        #pragma unroll
        for (int c = 0; c < JC1; ++c)
            s += dnP[((size_t)(c * BB + b) * SS + it * 32 + i) * HH + h];
        invd[h][i] = 0.125f / s;
    }

    short8 aq[HH][2];
    #pragma unroll
    for (int h = 0; h < HH; ++h)
        #pragma unroll
        for (int ks = 0; ks < 2; ++ks)
            aq[h][ks] = *reinterpret_cast<const short8*>(
                qws + (g0 + ih * 16 + m16) * EE + h * 64 + ks * 32 + quad * 8);

    f32x4 acc[2][8];
    #pragma unroll
    for (int mf = 0; mf < 2; ++mf)
        #pragma unroll
        for (int nf = 0; nf < 8; ++nf) acc[mf][nf] = (f32x4){0.f, 0.f, 0.f, 0.f};

    const int krow = tid >> 4, kcol = (tid & 15) * 32;
    // per-lane V row base: e = wv*128 + nf*16 + m16, k-offset = quad*8
    const __hip_bfloat16* vrow0 = vTg + ((size_t)b * EE + wv * 128 + m16) * SS + quad * 8;

    for (int st = 0; st < 16; ++st) {
        const int j0 = jc * 512 + st * 32;
        // stage K subtile [32 j][512 feat] (global -> reg -> LDS, short-lived temps)
        #pragma unroll
        for (int rr = 0; rr < 2; ++rr) {
            const uint4* src = reinterpret_cast<const uint4*>(
                kws + (gb + j0 + rr * 16 + krow) * EE + kcol);
            uint4* dst = reinterpret_cast<uint4*>(&KL[rr * 16 + krow][kcol]);
            dst[0] = src[0]; dst[1] = src[1]; dst[2] = src[2]; dst[3] = src[3];
        }
        __syncthreads();                       // KL ready; prev-step PV done w/ ewT

        // scores: wave's (ih, jh) quadrant of the 32x32 tile, all heads
        float wsum[4] = {0.f, 0.f, 0.f, 0.f};
        #pragma unroll
        for (int h = 0; h < HH; ++h) {
            const short8 b0 = *reinterpret_cast<const short8*>(
                &KL[jh * 16 + m16][h * 64 + quad * 8]);
            const short8 b1 = *reinterpret_cast<const short8*>(
                &KL[jh * 16 + m16][h * 64 + 32 + quad * 8]);
            f32x4 c = {0.f, 0.f, 0.f, 0.f};
            c = __builtin_amdgcn_mfma_f32_16x16x32_bf16(aq[h][0], b0, c, 0, 0, 0);
            c = __builtin_amdgcn_mfma_f32_16x16x32_bf16(aq[h][1], b1, c, 0, 0, 0);
            #pragma unroll
            for (int r = 0; r < 4; ++r)
                wsum[r] += __expf(c[r] * 0.125f) * invd[h][ih * 16 + quad * 4 + r];
        }
        #pragma unroll
        for (int r = 0; r < 4; ++r) {
            const __hip_bfloat16 wb = __float2bfloat16(wsum[r]);
            ewT[ih * 16 + quad * 4 + r][jh * 16 + m16] = wb;
            if ((float)wb > 0.1f) {            // rare: adjacency crossing
                const int li = ih * 16 + quad * 4 + r;
                const int idx = atomicAdd(&cntI[g0 + li], 1);
                if (idx < 16) {
                    slotJ[((size_t)g0 + li) * 16 + idx] = j0 + jh * 16 + m16;
                    slotW[((size_t)g0 + li) * 16 + idx] = (float)wb;
                }
            }
        }
        __syncthreads();                       // ewT ready

        // PV: V B-frags straight from global (L2-resident), consumed immediately
        {
            short8 vb[8];
            #pragma unroll
            for (int nf = 0; nf < 8; ++nf)
                vb[nf] = *reinterpret_cast<const short8*>(vrow0 + (size_t)(nf * 16) * SS + j0);
            const short8 a0 = *reinterpret_cast<const short8*>(&ewT[m16][quad * 8]);
            const short8 a1 = *reinterpret_cast<const short8*>(&ewT[16 + m16][quad * 8]);
            #pragma unroll
            for (int nf = 0; nf < 8; ++nf) {
                acc[0][nf] = __builtin_amdgcn_mfma_f32_16x16x32_bf16(a0, vb[nf], acc[0][nf], 0, 0, 0);
                acc[1][nf] = __builtin_amdgcn_mfma_f32_16x16x32_bf16(a1, vb[nf], acc[1][nf], 0, 0, 0);
            }
        }
    }

    // epilogue: bounce acc through KL for coalesced bf16 writes
    #pragma unroll
    for (int mf = 0; mf < 2; ++mf)
        #pragma unroll
        for (int nf = 0; nf < 8; ++nf)
            #pragma unroll
            for (int r = 0; r < 4; ++r)
                KL[mf * 16 + quad * 4 + r][wv * 128 + nf * 16 + m16] =
                    __float2bfloat16(acc[mf][nf][r]);
    __syncthreads();
    const int orow = tid >> 3;
    const int oc = (tid & 7) * 64;
    const uint4* s = reinterpret_cast<const uint4*>(&KL[orow][oc]);
    uint4* d = reinterpret_cast<uint4*>(
        pvP + ((size_t)jc * NN + g0 + orow) * EE + oc);
    #pragma unroll
    for (int q = 0; q < 8; ++q) d[q] = s[q];
}

// ---------------- K3: combine PV partials + rare messages path ----------------
__global__ __launch_bounds__(256) void pv_combine(
    const __hip_bfloat16* __restrict__ pvP,
    const int* __restrict__ cntI,
    const int* __restrict__ slotJ,
    const float* __restrict__ slotW,
    const float* __restrict__ x,
    __hip_bfloat16* __restrict__ u1out)
{
    const int tid = threadIdx.x;
    const int row = blockIdx.x * 4 + (tid >> 6);   // [0, NN)
    const int e0 = (tid & 63) * 8;
    float s[8] = {0.f, 0.f, 0.f, 0.f, 0.f, 0.f, 0.f, 0.f};
    #pragma unroll
    for (int c = 0; c < JCP; ++c) {
        const short8 v = *reinterpret_cast<const short8*>(
            pvP + ((size_t)c * NN + row) * EE + e0);
        #pragma unroll
        for (int k = 0; k < 8; ++k) s[k] += b2f(v[k]);
    }
    const int cn = cntI[row];
    if (cn > 0) {                                  // exact rare path: masked mean
        const float inv = 1.f / (float)cn;
        const int ns = cn < 16 ? cn : 16;
        const int b = row >> 11;
        for (int t = 0; t < ns; ++t) {
            const int j = slotJ[(size_t)row * 16 + t];
            const float w = slotW[(size_t)row * 16 + t] * inv;
            const float* xr = x + ((size_t)b * SS + j) * EE + e0;
            #pragma unroll
            for (int k = 0; k < 8; ++k) s[k] += w * xr[k];
        }
    }
    short8 o;
    #pragma unroll
    for (int k = 0; k < 8; ++k) o[k] = (short)f2bf(s[k]);
    *reinterpret_cast<short8*>(u1out + (size_t)row * EE + e0) = o;
}

extern "C" void kernel_launch(void* const* d_in, const int* in_sizes, int n_in,
                              void* d_out, int out_size, void* d_ws, size_t ws_size,
                              hipStream_t stream)
{
    const float* x   = (const float*)d_in[0];
    const float* Wq  = (const float*)d_in[1];
    const float* bq  = (const float*)d_in[2];
    const float* Wk  = (const float*)d_in[3];
    const float* bk  = (const float*)d_in[4];
    const float* Wv  = (const float*)d_in[5];
    const float* bv  = (const float*)d_in[6];
    const float* Wm1 = (const float*)d_in[7];
    const float* bm1 = (const float*)d_in[8];
    const float* Wm2 = (const float*)d_in[9];
    const float* bm2 = (const float*)d_in[10];
    const float* Wo  = (const float*)d_in[11];
    const float* bo  = (const float*)d_in[12];

    char* ws = (char*)d_ws;
    const size_t MB = 1024 * 1024;
    __hip_bfloat16* qb = (__hip_bfloat16*)(ws + 0);        // q -> u1 -> t   4MB
    __hip_bfloat16* kb = (__hip_bfloat16*)(ws + 4*MB);     // k -> hm        4MB
    __hip_bfloat16* vT = (__hip_bfloat16*)(ws + 8*MB);     // V^T [b][e][j]  4MB
    __hip_bfloat16* pvP = (__hip_bfloat16*)(ws + 12*MB);   // PV partials [4][NN][EE] 16MB
    float* dnP = (float*)(ws + 28*MB);                     // denom partials 1MB
    int*   cntI = (int*)(ws + 29*MB);                      // neighbor cnt  16KB
    int*   slotJ = (int*)(ws + 29*MB + 64*1024);           // crossing j    256KB
    float* slotW = (float*)(ws + 29*MB + 384*1024);        // crossing w    256KB
    const bool EXT = (ws_size >= 38 * MB);
    __hip_bfloat16* xb   = (__hip_bfloat16*)(ws + 30*MB);          // 4MB
    __hip_bfloat16* wqb  = (__hip_bfloat16*)(ws + 34*MB);
    __hip_bfloat16* wkb  = (__hip_bfloat16*)(ws + 34*MB + 512*1024);
    __hip_bfloat16* wvb  = (__hip_bfloat16*)(ws + 35*MB);
    __hip_bfloat16* wm1b = (__hip_bfloat16*)(ws + 35*MB + 512*1024);
    __hip_bfloat16* wm2b = (__hip_bfloat16*)(ws + 36*MB + 256*1024);
    __hip_bfloat16* wob  = (__hip_bfloat16*)(ws + 36*MB + 768*1024);

    dim3 blk(256, 1, 1);
    dim3 gg(EE / 64, NN / 64, 1);

    if (EXT) {
        conv_bf16<<<dim3(2048, 7, 1), blk, 0, stream>>>(
            x, Wq, Wk, Wv, Wm1, Wm2, Wo, xb, wqb, wkb, wvb, wm1b, wm2b, wob);
        qkv_gemm<1><<<dim3(24, NN / 64, 1), blk, 0, stream>>>(
            xb, wqb, bq, wkb, bk, wvb, bv, qb, kb, vT);
    } else {
        qkv_gemm<0><<<dim3(24, NN / 64, 1), blk, 0, stream>>>(
            x, Wq, bq, Wk, bk, Wv, bv, qb, kb, vT);
    }
    attn_denoms<<<dim3(JC1, SS / 64, BB), blk, 0, stream>>>(qb, kb, dnP, cntI);
    attn_ewpv<<<dim3(JCP, SS / 32, BB), blk, 0, stream>>>(
        qb, kb, vT, dnP, cntI, slotJ, slotW, pvP);
    pv_combine<<<dim3(NN / 4, 1, 1), blk, 0, stream>>>(
        pvP, cntI, slotJ, slotW, x, qb);                            // u1 -> qb
    if (EXT) {
        gemm_bt<1,1,1,0><<<gg, blk, 0, stream>>>(xb, wm1b, bm1, kb, EE + HH);
        gemm_bt<2,1,1,0><<<gg, blk, 0, stream>>>(kb, wm2b, bm2, qb, EE);
        gemm_bt<0,1,1,1><<<gg, blk, 0, stream>>>(qb, wob, bo, d_out, EE);
    } else {
        gemm_bt<1,0,0,0><<<gg, blk, 0, stream>>>(x, Wm1, bm1, kb, EE + HH);
        gemm_bt<2,1,0,0><<<gg, blk, 0, stream>>>(kb, Wm2, bm2, qb, EE);
        gemm_bt<0,1,0,1><<<gg, blk, 0, stream>>>(qb, Wo, bo, d_out, EE);
    }
}